// Round 3
// baseline (1177.518 us; speedup 1.0000x reference)
//
#include <hip/hip_runtime.h>
#include <math.h>

// ---------------------------------------------------------------------------
// OctreeAttention fused, round 3 (= round 2 + k_prep wproj index fix):
//   K0 weight prep (bf16 transpose; wproj stored [out_col][k], k in the
//                   interleaved cpos order K1 emits)
//   K1 qkv GEMM + RoPE + attention  (A-frags in registers, 80.9 KB LDS,
//                                    2 blocks/CU via __launch_bounds__(512,4))
//   K2 proj GEMM                    (no LDS, A-frags direct from global)
// d_out doubles as scratch: K1 writes bf16 attn-out into the first half of
// each block's own 128KB output region; K2 reads it fully into registers,
// barriers, then overwrites the region with f32. No cross-block overlap.
// ---------------------------------------------------------------------------

typedef float  float4v __attribute__((ext_vector_type(4)));
typedef short  bf16x8  __attribute__((ext_vector_type(8)));   // 8 bf16 = 4 VGPR

#define SCALE_ 0.17677669529663687f   // 32^-0.5

__device__ __forceinline__ unsigned short f2bf(float x) {
  union { float f; unsigned u; } v; v.f = x;
  unsigned r = v.u + 0x7FFFu + ((v.u >> 16) & 1u);   // RNE
  return (unsigned short)(r >> 16);
}
__device__ __forceinline__ unsigned pack2bf(float lo, float hi) {
  return (unsigned)f2bf(lo) | ((unsigned)f2bf(hi) << 16);
}
__device__ __forceinline__ float4v mfma16(bf16x8 a, bf16x8 b, float4v c) {
  return __builtin_amdgcn_mfma_f32_16x16x32_bf16(a, b, c, 0, 0, 0);
}

// ------------------------------- K0: weights -------------------------------
// wqkv_t[co][ci] = bf16(Wqkv[ci][co])                         (768 x 256)
// wproj_t[co][cpos] = bf16(Wproj[perm(cpos)][co])             (256 x 256)
//   row = OUTPUT column co (contiguous in k), inner index cpos is the
//   interleaved feature order K1's attention output uses:
//   perm(cpos) = h*32 + f,  h = cpos>>5, ww = cpos&31,
//   f = (ww&1) ? 16+(ww>>1) : (ww>>1)
__global__ __launch_bounds__(256) void k_prep(const float* __restrict__ wqkv,
                                              const float* __restrict__ wproj,
                                              unsigned short* __restrict__ wq,
                                              unsigned short* __restrict__ wp) {
  int tid = blockIdx.x * 256 + threadIdx.x;
  if (tid < 768 * 256) {
    int co = tid >> 8, ci = tid & 255;
    wq[tid] = f2bf(wqkv[ci * 768 + co]);
  } else {
    int u = tid - 768 * 256;
    int co = u >> 8, cpos = u & 255;          // row = output col, inner = k
    int h = cpos >> 5, ww = cpos & 31;
    int f = (ww & 1) ? 16 + (ww >> 1) : (ww >> 1);
    wp[u] = f2bf(wproj[(h * 32 + f) * 256 + co]);
  }
}

// ------------------------------- K1: fused ---------------------------------
// LDS map (unsigned short units):
//   QK_s [4][128][40] @ 0      q_h0,q_h1,k_h0,k_h1; cols feature-interleaved
//   VT_s [2][32][136] @ 20480  V^T [f][128], k-positions cpos-permuted
//   PL_s [8][32][40]  @ 29184  per-wave P (k-interleaved)
//   ML_s int[128]     @ 39424  depths, prow order
//   XYZ_s f32[384]    @ 39680  xyz, row order
// total 40448 us = 80896 B  -> 2 blocks/CU
#define K1_LDS_BYTES 80896

__global__ __launch_bounds__(512, 4) void k_fused(
    const float* __restrict__ data, const float* __restrict__ xyz,
    const int* __restrict__ depth, const float* __restrict__ bqkv,
    const float* __restrict__ freqs, const unsigned short* __restrict__ wqkv_t,
    unsigned short* __restrict__ aout /* d_out viewed as bf16 */) {
  extern __shared__ unsigned short smem[];
  unsigned short* QK_s = smem;
  unsigned short* VT_s = smem + 20480;
  unsigned short* PL_s = smem + 29184;
  int*   ML_s  = (int*)(smem + 39424);
  float* XYZ_s = (float*)(smem + 39680);

  const int b    = blockIdx.x;
  const int t    = threadIdx.x;
  const int lane = t & 63;
  const int w    = t >> 6;         // wave 0..7
  const int wm   = w >> 1;         // row quarter (32 rows) == attention group
  const int wn   = w & 1;          // col half of the 192-col qkv strip
  const int g    = lane >> 4;      // 0..3
  const int l15  = lane & 15;

  // stage depths (prow order: prow = d*32+kk <-> n_local = kk*4+d) and xyz
  if (t < 128) ML_s[t] = depth[b * 128 + ((t & 31) << 2) + (t >> 5)];
  if (t < 384) XYZ_s[t] = xyz[(size_t)b * 384 + t];

  // ---- A-fragments in registers (reused by all 4 head-pair iterations)
  bf16x8 areg[2][8];
  {
    const float* dbase = data + (size_t)b * 32768;
#pragma unroll
    for (int r = 0; r < 2; ++r) {
      const float* rp = dbase + (wm * 32 + r * 16 + l15) * 256 + 8 * g;
#pragma unroll
      for (int t8 = 0; t8 < 8; ++t8) {
        float4v u0 = *reinterpret_cast<const float4v*>(rp + 32 * t8);
        float4v u1 = *reinterpret_cast<const float4v*>(rp + 32 * t8 + 4);
        bf16x8 fr;
        fr[0] = (short)f2bf(u0.x); fr[1] = (short)f2bf(u0.y);
        fr[2] = (short)f2bf(u0.z); fr[3] = (short)f2bf(u0.w);
        fr[4] = (short)f2bf(u1.x); fr[5] = (short)f2bf(u1.y);
        fr[6] = (short)f2bf(u1.z); fr[7] = (short)f2bf(u1.w);
        areg[r][t8] = fr;
      }
    }
  }
  __syncthreads();

  for (int hp = 0; hp < 4; ++hp) {
    // ---- GEMM: 3 passes, one 32-col (f,f+16)-pair strip each
#pragma unroll
    for (int p = 0; p < 3; ++p) {
      const int nl0   = wn * 96 + p * 32;
      const int strip = nl0 >> 6;          // 0=q 1=k 2=v
      const int hloc  = (nl0 >> 5) & 1;    // head within pair
      const int cm0   = hp * 64 + (nl0 & 63) + l15;
      const int bro0  = strip * 256 + cm0;
      const unsigned short* bp0 = wqkv_t + (size_t)bro0 * 256 + 8 * g;
      const unsigned short* bp1 = bp0 + 16 * 256;
      float4v acc[2][2];
#pragma unroll
      for (int mt = 0; mt < 2; ++mt)
#pragma unroll
        for (int j = 0; j < 2; ++j) acc[mt][j] = (float4v){0.f, 0.f, 0.f, 0.f};
#pragma unroll
      for (int s = 0; s < 8; ++s) {
        bf16x8 b0 = *reinterpret_cast<const bf16x8*>(bp0 + 32 * s);
        bf16x8 b1 = *reinterpret_cast<const bf16x8*>(bp1 + 32 * s);
        acc[0][0] = mfma16(areg[0][s], b0, acc[0][0]);
        acc[0][1] = mfma16(areg[0][s], b1, acc[0][1]);
        acc[1][0] = mfma16(areg[1][s], b0, acc[1][0]);
        acc[1][1] = mfma16(areg[1][s], b1, acc[1][1]);
      }
      const float bb0 = bqkv[strip * 256 + cm0];
      const float bb1 = bqkv[strip * 256 + cm0 + 16];
      if (strip < 2) {
        const float* fp = freqs + ((hp * 2 + hloc) * 16 + l15) * 3;
        const float F0 = fp[0], F1 = fp[1], F2 = fp[2];
        unsigned short* dst = QK_s + (strip * 2 + hloc) * 5120;
#pragma unroll
        for (int mt = 0; mt < 2; ++mt)
#pragma unroll
          for (int rr = 0; rr < 4; ++rr) {
            const int row  = wm * 32 + mt * 16 + 4 * g + rr;
            const int prow = ((row & 3) << 5) | (row >> 2);
            const float v0 = acc[mt][0][rr] + bb0;
            const float v1 = acc[mt][1][rr] + bb1;
            const float th = XYZ_s[row * 3] * F0 + XYZ_s[row * 3 + 1] * F1 +
                             XYZ_s[row * 3 + 2] * F2;
            float sn, cs;
            __sincosf(th, &sn, &cs);
            *reinterpret_cast<unsigned*>(dst + prow * 40 + 2 * l15) =
                pack2bf(v0 * cs - v1 * sn, v1 * cs + v0 * sn);
          }
      } else {
        unsigned short* dst = VT_s + hloc * 4352;
#pragma unroll
        for (int mt = 0; mt < 2; ++mt)
#pragma unroll
          for (int rr = 0; rr < 4; ++rr) {
            const int row = wm * 32 + mt * 16 + 4 * g + rr;
            const int kk  = row >> 2;           // 0..31
            const int dd  = row & 3;            // group
            const int cpos = (kk < 16) ? (kk << 1) : (((kk - 16) << 1) | 1);
            dst[l15 * 136 + dd * 32 + cpos]        = f2bf(acc[mt][0][rr] + bb0);
            dst[(l15 + 16) * 136 + dd * 32 + cpos] = f2bf(acc[mt][1][rr] + bb1);
          }
      }
    }
    __syncthreads();

    // ---- attention: wave handles (group wm, head h = 2hp + wn)
    {
      const unsigned short* qm = QK_s + wn * 5120;
      const unsigned short* km = QK_s + (2 + wn) * 5120;
      bf16x8 aq0 = *reinterpret_cast<const bf16x8*>(qm + (wm * 32 + l15) * 40 + 8 * g);
      bf16x8 aq1 = *reinterpret_cast<const bf16x8*>(qm + (wm * 32 + 16 + l15) * 40 + 8 * g);
      bf16x8 bk0 = *reinterpret_cast<const bf16x8*>(km + (wm * 32 + l15) * 40 + 8 * g);
      bf16x8 bk1 = *reinterpret_cast<const bf16x8*>(km + (wm * 32 + 16 + l15) * 40 + 8 * g);
      float4v s_[2][2];
      s_[0][0] = s_[0][1] = s_[1][0] = s_[1][1] = (float4v){0.f, 0.f, 0.f, 0.f};
      s_[0][0] = mfma16(aq0, bk0, s_[0][0]);
      s_[0][1] = mfma16(aq0, bk1, s_[0][1]);
      s_[1][0] = mfma16(aq1, bk0, s_[1][0]);
      s_[1][1] = mfma16(aq1, bk1, s_[1][1]);

      const int mk0 = ML_s[wm * 32 + l15];
      const int mk1 = ML_s[wm * 32 + 16 + l15];
      unsigned short* plw = PL_s + w * 1280;
      float rs[2][4];
#pragma unroll
      for (int mt = 0; mt < 2; ++mt)
#pragma unroll
        for (int rr = 0; rr < 4; ++rr) {
          const int q_idx = mt * 16 + 4 * g + rr;
          const int mq = ML_s[wm * 32 + q_idx];
          // scores are O(0.1) here -> exp without max-subtraction is safe
          const float sv0 = s_[mt][0][rr] * SCALE_ + (mq < mk0 ? -1000.f : 0.f);
          const float sv1 = s_[mt][1][rr] * SCALE_ + (mq < mk1 ? -1000.f : 0.f);
          const float p0 = __expf(sv0);
          const float p1 = __expf(sv1);
          float sm = p0 + p1;
          sm += __shfl_xor(sm, 1);
          sm += __shfl_xor(sm, 2);
          sm += __shfl_xor(sm, 4);
          sm += __shfl_xor(sm, 8);
          rs[mt][rr] = 1.0f / sm;
          *reinterpret_cast<unsigned*>(plw + q_idx * 40 + 2 * l15) = pack2bf(p0, p1);
        }
      bf16x8 ap0 = *reinterpret_cast<const bf16x8*>(plw + l15 * 40 + 8 * g);
      bf16x8 ap1 = *reinterpret_cast<const bf16x8*>(plw + (16 + l15) * 40 + 8 * g);
      const unsigned short* vt = VT_s + wn * 4352;
      bf16x8 bv0 = *reinterpret_cast<const bf16x8*>(vt + l15 * 136 + wm * 32 + 8 * g);
      bf16x8 bv1 = *reinterpret_cast<const bf16x8*>(vt + (16 + l15) * 136 + wm * 32 + 8 * g);
      float4v o_[2][2];
      o_[0][0] = o_[0][1] = o_[1][0] = o_[1][1] = (float4v){0.f, 0.f, 0.f, 0.f};
      o_[0][0] = mfma16(ap0, bv0, o_[0][0]);
      o_[0][1] = mfma16(ap0, bv1, o_[0][1]);
      o_[1][0] = mfma16(ap1, bv0, o_[1][0]);
      o_[1][1] = mfma16(ap1, bv1, o_[1][1]);

      const int h = hp * 2 + wn;
      unsigned short* ob = aout + (size_t)b * 65536 + h * 32;
#pragma unroll
      for (int mt = 0; mt < 2; ++mt)
#pragma unroll
        for (int rr = 0; rr < 4; ++rr) {
          const int q_idx = mt * 16 + 4 * g + rr;
          const float r = rs[mt][rr];
          // packed interleaved feature order (matches wproj_t inner-index perm)
          *reinterpret_cast<unsigned*>(ob + (size_t)(q_idx * 4 + wm) * 256 + 2 * l15) =
              pack2bf(o_[mt][0][rr] * r, o_[mt][1][rr] * r);
        }
    }
    __syncthreads();
  }
}

// ------------------------------- K2: proj ----------------------------------
__global__ __launch_bounds__(512, 4) void k_proj(
    const unsigned short* ain,                       // d_out bf16 (aliases out!)
    const unsigned short* __restrict__ wproj_t,
    const float* __restrict__ bproj,
    float* out) {
  const int b = blockIdx.x, t = threadIdx.x;
  const int lane = t & 63, w = t >> 6;
  const int wm = w >> 1, wn = w & 1;
  const int g = lane >> 4, l15 = lane & 15;

  // A-fragments straight from global (bf16, already frag-shaped; k = cpos order)
  bf16x8 areg[2][8];
  const unsigned short* abase = ain + (size_t)b * 65536;
#pragma unroll
  for (int r = 0; r < 2; ++r) {
    const unsigned short* rp = abase + (wm * 32 + r * 16 + l15) * 256 + 8 * g;
#pragma unroll
    for (int t8 = 0; t8 < 8; ++t8)
      areg[r][t8] = *reinterpret_cast<const bf16x8*>(rp + 32 * t8);
  }
  // all reads of this block's region complete before anyone overwrites it
  // (__syncthreads drains vmcnt before s_barrier)
  __syncthreads();

#pragma unroll
  for (int pass = 0; pass < 4; ++pass) {
    const int colbase = wn * 128 + pass * 32;
    const unsigned short* bp0 = wproj_t + (size_t)(colbase + l15) * 256 + 8 * g;
    const unsigned short* bp1 = bp0 + 16 * 256;
    float4v acc[2][2];
#pragma unroll
    for (int mt = 0; mt < 2; ++mt)
#pragma unroll
      for (int j = 0; j < 2; ++j) acc[mt][j] = (float4v){0.f, 0.f, 0.f, 0.f};
#pragma unroll
    for (int s = 0; s < 8; ++s) {
      bf16x8 b0 = *reinterpret_cast<const bf16x8*>(bp0 + 32 * s);
      bf16x8 b1 = *reinterpret_cast<const bf16x8*>(bp1 + 32 * s);
      acc[0][0] = mfma16(areg[0][s], b0, acc[0][0]);
      acc[0][1] = mfma16(areg[0][s], b1, acc[0][1]);
      acc[1][0] = mfma16(areg[1][s], b0, acc[1][0]);
      acc[1][1] = mfma16(areg[1][s], b1, acc[1][1]);
    }
#pragma unroll
    for (int j = 0; j < 2; ++j) {
      const int col = colbase + j * 16 + l15;
      const float bb = bproj[col];
#pragma unroll
      for (int mt = 0; mt < 2; ++mt)
#pragma unroll
        for (int rr = 0; rr < 4; ++rr) {
          const int row = wm * 32 + mt * 16 + 4 * g + rr;
          out[((size_t)b * 128 + row) * 256 + col] = acc[mt][j][rr] + bb;
        }
    }
  }
}

// ----------------------------- launch --------------------------------------
extern "C" void kernel_launch(void* const* d_in, const int* in_sizes, int n_in,
                              void* d_out, int out_size, void* d_ws, size_t ws_size,
                              hipStream_t stream) {
  const float* data  = (const float*)d_in[0];
  const float* xyz   = (const float*)d_in[1];
  const int*   depth = (const int*)d_in[2];
  const float* wqkv  = (const float*)d_in[3];
  const float* bqkv  = (const float*)d_in[4];
  const float* wproj = (const float*)d_in[5];
  const float* bproj = (const float*)d_in[6];
  const float* freqs = (const float*)d_in[7];

  unsigned short* wqkv_t  = (unsigned short*)d_ws;          // [768][256] bf16
  unsigned short* wproj_t = wqkv_t + 768 * 256;             // [256][256] bf16 (k-permuted)

  (void)hipFuncSetAttribute(reinterpret_cast<const void*>(k_fused),
                            hipFuncAttributeMaxDynamicSharedMemorySize, K1_LDS_BYTES);

  k_prep<<<dim3(1024), dim3(256), 0, stream>>>(wqkv, wproj, wqkv_t, wproj_t);
  k_fused<<<dim3(3125), dim3(512), K1_LDS_BYTES, stream>>>(
      data, xyz, depth, bqkv, freqs, wqkv_t, (unsigned short*)d_out);
  k_proj<<<dim3(3125), dim3(512), 0, stream>>>(
      (const unsigned short*)d_out, wproj_t, bproj, (float*)d_out);
}

// Round 4
// 524.211 us; speedup vs baseline: 2.2463x; 2.2463x over previous
//
#include <hip/hip_runtime.h>
#include <math.h>

// ---------------------------------------------------------------------------
// OctreeAttention fused, round 4:
//  Root cause identified r1/r3: GEMM B-operands (weight rows, 512B-strided,
//  16 scattered lines per load, re-read 4x) serialize on L2 channels —
//  per-block time was identical at 1 or 2 blocks/CU. Fix: stage all weight
//  tiles into LDS with coalesced contiguous loads; read via XOR-swizzled
//  conflict-free ds_read_b128. Waves own 16 rows (areg=32 VGPR, no spill).
//  RoPE sin/cos via native v_sin/v_cos (fract-reduced) instead of ocml.
// ---------------------------------------------------------------------------

typedef float  float4v __attribute__((ext_vector_type(4)));
typedef short  bf16x8  __attribute__((ext_vector_type(8)));   // 8 bf16 = 4 VGPR
typedef unsigned short us4 __attribute__((ext_vector_type(4)));

#define SCALE_ 0.17677669529663687f   // 32^-0.5
#define INV2PI 0.15915494309189535f

__device__ __forceinline__ unsigned short f2bf(float x) {
  union { float f; unsigned u; } v; v.f = x;
  unsigned r = v.u + 0x7FFFu + ((v.u >> 16) & 1u);   // RNE
  return (unsigned short)(r >> 16);
}
__device__ __forceinline__ unsigned pack2bf(float lo, float hi) {
  return (unsigned)f2bf(lo) | ((unsigned)f2bf(hi) << 16);
}
__device__ __forceinline__ float4v mfma16(bf16x8 a, bf16x8 b, float4v c) {
  return __builtin_amdgcn_mfma_f32_16x16x32_bf16(a, b, c, 0, 0, 0);
}
// XOR swizzle within 512B rows: spreads 512B-strided column reads across banks
__device__ __forceinline__ int swz(int off) {
  return off ^ (((off >> 9) & 7) << 4);
}

// ------------------------------- K0: weights -------------------------------
// wqkv_t[co][ci] = bf16(Wqkv[ci][co])                         (768 x 256)
// wproj_t[co][cpos] = bf16(Wproj[perm(cpos)][co])             (256 x 256)
//   perm(cpos)=h*32+f, h=cpos>>5, ww=cpos&31, f=(ww&1)?16+(ww>>1):(ww>>1)
__global__ __launch_bounds__(256) void k_prep(const float* __restrict__ wqkv,
                                              const float* __restrict__ wproj,
                                              unsigned short* __restrict__ wq,
                                              unsigned short* __restrict__ wp) {
  int tid = blockIdx.x * 256 + threadIdx.x;
  if (tid < 768 * 256) {
    int co = tid >> 8, ci = tid & 255;
    wq[tid] = f2bf(wqkv[ci * 768 + co]);
  } else {
    int u = tid - 768 * 256;
    int co = u >> 8, cpos = u & 255;
    int h = cpos >> 5, ww = cpos & 31;
    int f = (ww & 1) ? 16 + (ww >> 1) : (ww >> 1);
    wp[u] = f2bf(wproj[(h * 32 + f) * 256 + co]);
  }
}

// ------------------------------- K1: fused ---------------------------------
// LDS (bytes):
//   B_s   @ 0      49152  3 weight tiles (q,k,v) [32][512B], swizzled
//                         (PL aliases [0,10240) after GEMM; A-restage
//                          aliases [0,65536) before the head loop)
//   QKq   @ 49152  10240  q [128 prow][80B] feature-pair interleaved
//   QKk   @ 59392  10240  k   "
//   VT    @ 69632   8704  V^T [32 f][272B], k in cpos order
//   ML    @ 78336    512  depths (prow order)
//   XYZ   @ 78848   1536  xyz f32 (row order)
//   F_s   @ 80384   1536  freqs f32
// total 81920 B (= 80 KiB)  -> 2 blocks/CU
#define K1_LDS_BYTES 81920

__global__ __launch_bounds__(512, 4) void k_fused(
    const float* __restrict__ data, const float* __restrict__ xyz,
    const int* __restrict__ depth, const float* __restrict__ bqkv,
    const float* __restrict__ freqs, const unsigned short* __restrict__ wqkv_t,
    unsigned short* __restrict__ aout /* d_out viewed as bf16 */) {
  extern __shared__ char smem[];
  const int b    = blockIdx.x;
  const int t    = threadIdx.x;
  const int lane = t & 63;
  const int w    = t >> 6;         // wave 0..7: owns point rows [16w,16w+16)
  const int g    = lane >> 4;      // 0..3
  const int l15  = lane & 15;
  const int d    = w >> 1;         // attention group for this wave
  const int half = w & 1;          // which 16 of the group's 32 prows

  // ---- stage small tables
  if (t < 128) ((int*)(smem + 78336))[t] =
      depth[b * 128 + ((t & 31) << 2) + (t >> 5)];          // prow order
  if (t < 384) ((float*)(smem + 78848))[t] = xyz[(size_t)b * 384 + t];
  if (t < 384) ((float*)(smem + 80384))[t] = freqs[t];

  // ---- A restage: coalesced f32 loads -> swizzled bf16 [128][512B] in LDS
  {
    const float* dbase = data + (size_t)b * 32768;
#pragma unroll
    for (int i = 0; i < 16; ++i) {
      const int fidx = i * 512 + t;                 // float4 index, contiguous
      const float4v v4 = *reinterpret_cast<const float4v*>(dbase + fidx * 4);
      us4 pk;
      pk.x = f2bf(v4.x); pk.y = f2bf(v4.y); pk.z = f2bf(v4.z); pk.w = f2bf(v4.w);
      *reinterpret_cast<us4*>(smem + swz(fidx * 8)) = pk;
    }
  }
  __syncthreads();

  // ---- A fragments -> registers (16 rows/wave, reused for all 8 heads)
  bf16x8 areg[8];
#pragma unroll
  for (int s = 0; s < 8; ++s)
    areg[s] = *reinterpret_cast<const bf16x8*>(
        smem + swz((16 * w + l15) * 512 + s * 64 + g * 16));

  // hoist depth mask values (ML_s is ready after the barrier above)
  const int* ML = (const int*)(smem + 78336);
  int mq[4];
#pragma unroll
  for (int rr = 0; rr < 4; ++rr) mq[rr] = ML[32 * d + 16 * half + 4 * g + rr];
  const int mk0 = ML[32 * d + l15];
  const int mk1 = ML[32 * d + 16 + l15];
  __syncthreads();   // A region free -> becomes weight-tile region

#pragma unroll 1
  for (int h = 0; h < 8; ++h) {
    // ---- stage weight tiles q,k,v: rows [s*256+32h, +32) of wqkv_t, 16KB each
    {
      const char* wb = (const char*)(wqkv_t) + (size_t)h * 32 * 512;
      bf16x8 s0, s1, s2, s3, s4, s5;
      s0 = *reinterpret_cast<const bf16x8*>(wb + t * 16);
      s1 = *reinterpret_cast<const bf16x8*>(wb + 8192 + t * 16);
      s2 = *reinterpret_cast<const bf16x8*>(wb + 131072 + t * 16);
      s3 = *reinterpret_cast<const bf16x8*>(wb + 131072 + 8192 + t * 16);
      s4 = *reinterpret_cast<const bf16x8*>(wb + 262144 + t * 16);
      s5 = *reinterpret_cast<const bf16x8*>(wb + 262144 + 8192 + t * 16);
      const int o0 = swz(t * 16), o1 = swz(8192 + t * 16);
      *reinterpret_cast<bf16x8*>(smem + o0) = s0;
      *reinterpret_cast<bf16x8*>(smem + o1) = s1;
      *reinterpret_cast<bf16x8*>(smem + 16384 + o0) = s2;
      *reinterpret_cast<bf16x8*>(smem + 16384 + o1) = s3;
      *reinterpret_cast<bf16x8*>(smem + 32768 + o0) = s4;
      *reinterpret_cast<bf16x8*>(smem + 32768 + o1) = s5;
    }
    __syncthreads();

    // ---- GEMM q & k strips (share RoPE theta)
    {
      float4v aq0 = {0.f,0.f,0.f,0.f}, aq1 = aq0, ak0 = aq0, ak1 = aq0;
#pragma unroll
      for (int s = 0; s < 8; ++s) {
        const int ko = s * 64 + g * 16;
        bf16x8 bq0 = *reinterpret_cast<const bf16x8*>(smem + swz(l15 * 512 + ko));
        bf16x8 bq1 = *reinterpret_cast<const bf16x8*>(smem + swz((l15 + 16) * 512 + ko));
        bf16x8 bk0 = *reinterpret_cast<const bf16x8*>(smem + 16384 + swz(l15 * 512 + ko));
        bf16x8 bk1 = *reinterpret_cast<const bf16x8*>(smem + 16384 + swz((l15 + 16) * 512 + ko));
        aq0 = mfma16(areg[s], bq0, aq0);
        aq1 = mfma16(areg[s], bq1, aq1);
        ak0 = mfma16(areg[s], bk0, ak0);
        ak1 = mfma16(areg[s], bk1, ak1);
      }
      const float bq0v = bqkv[h * 32 + l15];
      const float bq1v = bqkv[h * 32 + 16 + l15];
      const float bk0v = bqkv[256 + h * 32 + l15];
      const float bk1v = bqkv[256 + h * 32 + 16 + l15];
      const float* Fp = (const float*)(smem + 80384) + (h * 16 + l15) * 3;
      const float F0 = Fp[0], F1 = Fp[1], F2 = Fp[2];
#pragma unroll
      for (int rr = 0; rr < 4; ++rr) {
        const int row = 16 * w + 4 * g + rr;
        const float* xp = (const float*)(smem + 78848) + row * 3;
        const float th = xp[0] * F0 + xp[1] * F1 + xp[2] * F2;
        float rev = th * INV2PI;
        rev -= floorf(rev);
        const float sn = __builtin_amdgcn_sinf(rev);
        const float cs = __builtin_amdgcn_cosf(rev);
        const int prow = ((row & 3) << 5) | (row >> 2);
        const float q0 = aq0[rr] + bq0v, q1 = aq1[rr] + bq1v;
        const float k0 = ak0[rr] + bk0v, k1 = ak1[rr] + bk1v;
        *reinterpret_cast<unsigned*>(smem + 49152 + prow * 80 + 4 * l15) =
            pack2bf(q0 * cs - q1 * sn, q1 * cs + q0 * sn);
        *reinterpret_cast<unsigned*>(smem + 59392 + prow * 80 + 4 * l15) =
            pack2bf(k0 * cs - k1 * sn, k1 * cs + k0 * sn);
      }
    }
    // ---- GEMM v strip -> VT (transposed, cpos-permuted keys)
    {
      float4v av0 = {0.f,0.f,0.f,0.f}, av1 = av0;
#pragma unroll
      for (int s = 0; s < 8; ++s) {
        const int ko = s * 64 + g * 16;
        bf16x8 bv0 = *reinterpret_cast<const bf16x8*>(smem + 32768 + swz(l15 * 512 + ko));
        bf16x8 bv1 = *reinterpret_cast<const bf16x8*>(smem + 32768 + swz((l15 + 16) * 512 + ko));
        av0 = mfma16(areg[s], bv0, av0);
        av1 = mfma16(areg[s], bv1, av1);
      }
      const float bv0v = bqkv[512 + h * 32 + l15];
      const float bv1v = bqkv[512 + h * 32 + 16 + l15];
#pragma unroll
      for (int rr = 0; rr < 4; ++rr) {
        const int row = 16 * w + 4 * g + rr;
        const int kk = row >> 2, dd = row & 3;
        const int cpos = (kk < 16) ? (kk << 1) : (((kk - 16) << 1) | 1);
        *reinterpret_cast<unsigned short*>(
            smem + 69632 + l15 * 272 + (dd * 32 + cpos) * 2) = f2bf(av0[rr] + bv0v);
        *reinterpret_cast<unsigned short*>(
            smem + 69632 + (l15 + 16) * 272 + (dd * 32 + cpos) * 2) = f2bf(av1[rr] + bv1v);
      }
    }
    __syncthreads();

    // ---- attention: wave handles (group d, rows 16*half..+16), head h
    {
      const bf16x8 aq = *reinterpret_cast<const bf16x8*>(
          smem + 49152 + (32 * d + 16 * half + l15) * 80 + 16 * g);
      const bf16x8 bk0 = *reinterpret_cast<const bf16x8*>(
          smem + 59392 + (32 * d + l15) * 80 + 16 * g);
      const bf16x8 bk1 = *reinterpret_cast<const bf16x8*>(
          smem + 59392 + (32 * d + 16 + l15) * 80 + 16 * g);
      float4v s0 = {0.f,0.f,0.f,0.f}, s1 = s0;
      s0 = mfma16(aq, bk0, s0);
      s1 = mfma16(aq, bk1, s1);

      char* plw = smem + w * 1280;     // aliases dead Bq weight tile
      float rs[4];
#pragma unroll
      for (int rr = 0; rr < 4; ++rr) {
        // scores are O(0.2) -> exp without max-subtraction is safe
        const float sv0 = s0[rr] * SCALE_ + (mq[rr] < mk0 ? -1000.f : 0.f);
        const float sv1 = s1[rr] * SCALE_ + (mq[rr] < mk1 ? -1000.f : 0.f);
        const float p0 = __expf(sv0);
        const float p1 = __expf(sv1);
        float sm = p0 + p1;
        sm += __shfl_xor(sm, 1);
        sm += __shfl_xor(sm, 2);
        sm += __shfl_xor(sm, 4);
        sm += __shfl_xor(sm, 8);
        rs[rr] = 1.0f / sm;
        *reinterpret_cast<unsigned*>(plw + (4 * g + rr) * 80 + 4 * l15) =
            pack2bf(p0, p1);
      }
      const bf16x8 ap = *reinterpret_cast<const bf16x8*>(plw + l15 * 80 + 16 * g);
      const bf16x8 bv0 = *reinterpret_cast<const bf16x8*>(
          smem + 69632 + l15 * 272 + d * 64 + 16 * g);
      const bf16x8 bv1 = *reinterpret_cast<const bf16x8*>(
          smem + 69632 + (l15 + 16) * 272 + d * 64 + 16 * g);
      float4v o0 = {0.f,0.f,0.f,0.f}, o1 = o0;
      o0 = mfma16(ap, bv0, o0);
      o1 = mfma16(ap, bv1, o1);

      char* ob = (char*)aout + (size_t)b * 131072 + h * 64;
#pragma unroll
      for (int rr = 0; rr < 4; ++rr) {
        const int n_local = (16 * half + 4 * g + rr) * 4 + d;
        *reinterpret_cast<unsigned*>(ob + n_local * 512 + 4 * l15) =
            pack2bf(o0[rr] * rs[rr], o1[rr] * rs[rr]);
      }
    }
    __syncthreads();   // PL/QK/VT reads done before next head's staging
  }
}

// ------------------------------- K2: proj ----------------------------------
// LDS: A (restaged attn-out, swizzled) @0 64KB, B tile @65536 16KB -> 80KB
#define K2_LDS_BYTES 81920

__global__ __launch_bounds__(512, 4) void k_proj(
    const unsigned short* ain,                       // d_out bf16 (aliases out!)
    const unsigned short* __restrict__ wproj_t,
    const float* __restrict__ bproj,
    float* out) {
  extern __shared__ char smem[];
  const int b = blockIdx.x, t = threadIdx.x;
  const int lane = t & 63, w = t >> 6;
  const int g = lane >> 4, l15 = lane & 15;

  // ---- A restage: coalesced bf16 loads -> swizzled LDS [128][512B]
  {
    const char* abase = (const char*)ain + (size_t)b * 131072;
    bf16x8 stg[8];
#pragma unroll
    for (int i = 0; i < 8; ++i)
      stg[i] = *reinterpret_cast<const bf16x8*>(abase + i * 8192 + t * 16);
#pragma unroll
    for (int i = 0; i < 8; ++i)
      *reinterpret_cast<bf16x8*>(smem + swz(i * 8192 + t * 16)) = stg[i];
  }
  __syncthreads();

  bf16x8 areg[8];
#pragma unroll
  for (int s = 0; s < 8; ++s)
    areg[s] = *reinterpret_cast<const bf16x8*>(
        smem + swz((16 * w + l15) * 512 + s * 64 + g * 16));

#pragma unroll 1
  for (int p = 0; p < 8; ++p) {
    // stage B tile: rows [32p, +32) of wproj_t (16KB contiguous)
    const char* wb = (const char*)wproj_t + p * 16384;
    const bf16x8 s0 = *reinterpret_cast<const bf16x8*>(wb + t * 16);
    const bf16x8 s1 = *reinterpret_cast<const bf16x8*>(wb + 8192 + t * 16);
    __syncthreads();               // prev pass's B reads done
    *reinterpret_cast<bf16x8*>(smem + 65536 + swz(t * 16)) = s0;
    *reinterpret_cast<bf16x8*>(smem + 65536 + swz(8192 + t * 16)) = s1;
    __syncthreads();

    float4v acc0 = {0.f,0.f,0.f,0.f}, acc1 = acc0;
#pragma unroll
    for (int s = 0; s < 8; ++s) {
      const int ko = s * 64 + g * 16;
      bf16x8 b0 = *reinterpret_cast<const bf16x8*>(smem + 65536 + swz(l15 * 512 + ko));
      bf16x8 b1 = *reinterpret_cast<const bf16x8*>(smem + 65536 + swz((l15 + 16) * 512 + ko));
      acc0 = mfma16(areg[s], b0, acc0);
      acc1 = mfma16(areg[s], b1, acc1);
    }
    const int col0 = 32 * p + l15, col1 = col0 + 16;
    const float bb0 = bproj[col0], bb1 = bproj[col1];
#pragma unroll
    for (int rr = 0; rr < 4; ++rr) {
      const int row = 16 * w + 4 * g + rr;
      out[((size_t)b * 128 + row) * 256 + col0] = acc0[rr] + bb0;
      out[((size_t)b * 128 + row) * 256 + col1] = acc1[rr] + bb1;
    }
  }
}

// ----------------------------- launch --------------------------------------
extern "C" void kernel_launch(void* const* d_in, const int* in_sizes, int n_in,
                              void* d_out, int out_size, void* d_ws, size_t ws_size,
                              hipStream_t stream) {
  const float* data  = (const float*)d_in[0];
  const float* xyz   = (const float*)d_in[1];
  const int*   depth = (const int*)d_in[2];
  const float* wqkv  = (const float*)d_in[3];
  const float* bqkv  = (const float*)d_in[4];
  const float* wproj = (const float*)d_in[5];
  const float* bproj = (const float*)d_in[6];
  const float* freqs = (const float*)d_in[7];

  unsigned short* wqkv_t  = (unsigned short*)d_ws;          // [768][256] bf16
  unsigned short* wproj_t = wqkv_t + 768 * 256;             // [256][256] bf16 (k-permuted)

  (void)hipFuncSetAttribute(reinterpret_cast<const void*>(k_fused),
                            hipFuncAttributeMaxDynamicSharedMemorySize, K1_LDS_BYTES);
  (void)hipFuncSetAttribute(reinterpret_cast<const void*>(k_proj),
                            hipFuncAttributeMaxDynamicSharedMemorySize, K2_LDS_BYTES);

  k_prep<<<dim3(1024), dim3(256), 0, stream>>>(wqkv, wproj, wqkv_t, wproj_t);
  k_fused<<<dim3(3125), dim3(512), K1_LDS_BYTES, stream>>>(
      data, xyz, depth, bqkv, freqs, wqkv_t, (unsigned short*)d_out);
  k_proj<<<dim3(3125), dim3(512), K2_LDS_BYTES, stream>>>(
      (const unsigned short*)d_out, wproj_t, bproj, (float*)d_out);
}

// Round 7
// 467.010 us; speedup vs baseline: 2.5214x; 1.1225x over previous
//
#include <hip/hip_runtime.h>
#include <math.h>

// ---------------------------------------------------------------------------
// OctreeAttention fused, round 6 = round 4 (PASSED, 524us) + two verified
// grafts, everything else verbatim:
//   (1) k_prep emits wqkv in MFMA fragment order -> k_fused B-staging is a
//       linear copy and all GEMM B ds_reads are base+immediate (no swz VALU).
//   (2) softmax denominator via ones-MFMA row-sum (replaces 64 shfl/add per
//       wave*head) + v_rcp normalization; masks pre-hoisted as floats.
// r5's T14 barrier restructure and cvt_pk packing are intentionally DROPPED
// (unexplained r5 failure); 3-barrier/head structure, pack2bf, floorf kept.
// ---------------------------------------------------------------------------

typedef float  float4v __attribute__((ext_vector_type(4)));
typedef short  bf16x8  __attribute__((ext_vector_type(8)));   // 8 bf16 = 4 VGPR
typedef unsigned short us4 __attribute__((ext_vector_type(4)));

#define SCALE_ 0.17677669529663687f   // 32^-0.5
#define INV2PI 0.15915494309189535f

__device__ __forceinline__ unsigned short f2bf(float x) {
  union { float f; unsigned u; } v; v.f = x;
  unsigned r = v.u + 0x7FFFu + ((v.u >> 16) & 1u);   // RNE
  return (unsigned short)(r >> 16);
}
__device__ __forceinline__ unsigned pack2bf(float lo, float hi) {
  return (unsigned)f2bf(lo) | ((unsigned)f2bf(hi) << 16);
}
__device__ __forceinline__ float4v mfma16(bf16x8 a, bf16x8 b, float4v c) {
  return __builtin_amdgcn_mfma_f32_16x16x32_bf16(a, b, c, 0, 0, 0);
}
// XOR swizzle within 512B rows (A image + k_proj), r4-verbatim
__device__ __forceinline__ int swz(int off) {
  return off ^ (((off >> 9) & 7) << 4);
}

// ------------------------------- K0: weights -------------------------------
// wqf: fragment-ordered bf16 blob. element(h,mat,s,g,col,e) =
//   h*24576 + mat*8192 + s*1024 + g*256 + col*8 + e
//   holds Wqkv[ci][co] with ci = s*32+g*8+e, co = mat*256+h*32+col.
// wproj_t[co][cpos] = bf16(Wproj[perm(cpos)][co])  (r4-verbatim):
//   perm(cpos)=hh*32+f, hh=cpos>>5, ww=cpos&31, f=(ww&1)?16+(ww>>1):(ww>>1)
__global__ __launch_bounds__(256) void k_prep(const float* __restrict__ wqkv,
                                              const float* __restrict__ wproj,
                                              unsigned short* __restrict__ wqf,
                                              unsigned short* __restrict__ wp) {
  int tid = blockIdx.x * 256 + threadIdx.x;
  if (tid < 768 * 256) {
    int h  = tid / 24576;
    int r  = tid - h * 24576;
    int mat = r >> 13;
    int r2  = r & 8191;
    int s = r2 >> 10, g = (r2 >> 8) & 3, col = (r2 >> 3) & 31, e = r2 & 7;
    int ci = s * 32 + g * 8 + e;
    int co = mat * 256 + h * 32 + col;
    wqf[tid] = f2bf(wqkv[ci * 768 + co]);
  } else {
    int u = tid - 768 * 256;
    int co = u >> 8, cpos = u & 255;
    int hh = cpos >> 5, ww = cpos & 31;
    int f = (ww & 1) ? 16 + (ww >> 1) : (ww >> 1);
    wp[u] = f2bf(wproj[(hh * 32 + f) * 256 + co]);
  }
}

// ------------------------------- K1: fused ---------------------------------
// LDS (bytes), r4-verbatim map:
//   B_s   @ 0      49152  3 frag-order weight tiles (q,k,v) 16KB each
//                         (PL aliases [0,10240) after GEMM; A-image (swz)
//                          aliases [0,65536) in the prologue)
//   QKq   @ 49152  10240  q [128 prow][80B] feature-pair interleaved
//   QKk   @ 59392  10240  k   "
//   VT    @ 69632   8704  V^T [32 f][272B], keys cpos-interleaved
//   ML    @ 78336    512  depths (prow order)
//   XYZ   @ 78848   1536  xyz f32 (row order)
//   F_s   @ 80384   1536  freqs f32
#define K1_LDS_BYTES 81920

__global__ __launch_bounds__(512, 4) void k_fused(
    const float* __restrict__ data, const float* __restrict__ xyz,
    const int* __restrict__ depth, const float* __restrict__ bqkv,
    const float* __restrict__ freqs, const unsigned short* __restrict__ wqf,
    unsigned short* __restrict__ aout /* d_out viewed as bf16 */) {
  extern __shared__ char smem[];
  const int b    = blockIdx.x;
  const int t    = threadIdx.x;
  const int lane = t & 63;
  const int w    = t >> 6;         // wave 0..7: owns point rows [16w,16w+16)
  const int g    = lane >> 4;      // 0..3
  const int l15  = lane & 15;
  const int d    = w >> 1;         // attention group
  const int half = w & 1;          // 16-row half within group

  // ---- stage small tables (r4-verbatim)
  if (t < 128) ((int*)(smem + 78336))[t] =
      depth[b * 128 + ((t & 31) << 2) + (t >> 5)];          // prow order
  if (t < 384) ((float*)(smem + 78848))[t] = xyz[(size_t)b * 384 + t];
  if (t < 384) ((float*)(smem + 80384))[t] = freqs[t];

  // ---- A restage: coalesced f32 loads -> swizzled bf16 [128][512B] (r4)
  {
    const float* dbase = data + (size_t)b * 32768;
#pragma unroll
    for (int i = 0; i < 16; ++i) {
      const int fidx = i * 512 + t;
      const float4v v4 = *reinterpret_cast<const float4v*>(dbase + fidx * 4);
      us4 pk;
      pk.x = f2bf(v4.x); pk.y = f2bf(v4.y); pk.z = f2bf(v4.z); pk.w = f2bf(v4.w);
      *reinterpret_cast<us4*>(smem + swz(fidx * 8)) = pk;
    }
  }
  __syncthreads();

  // ---- A fragments -> registers (r4-verbatim)
  bf16x8 areg[8];
#pragma unroll
  for (int s = 0; s < 8; ++s)
    areg[s] = *reinterpret_cast<const bf16x8*>(
        smem + swz((16 * w + l15) * 512 + s * 64 + g * 16));

  // ---- masks hoisted as floats (graft 3)
  float maskf0[4], maskf1[4];
  {
    const int* ML = (const int*)(smem + 78336);
    const int mk0 = ML[32 * d + l15];
    const int mk1 = ML[32 * d + 16 + l15];
#pragma unroll
    for (int rr = 0; rr < 4; ++rr) {
      const int mq = ML[32 * d + 16 * half + 4 * g + rr];
      maskf0[rr] = (mq < mk0) ? -1000.f : 0.f;
      maskf1[rr] = (mq < mk1) ? -1000.f : 0.f;
    }
  }
  // ones B-fragment for softmax row-sum via MFMA (graft 2)
  bf16x8 ones;
#pragma unroll
  for (int j = 0; j < 8; ++j) ones[j] = (short)0x3F80;

  __syncthreads();   // A region free -> becomes weight-tile region

  const int bb = g * 512 + l15 * 16;     // frag B read base (graft 1)

#pragma unroll 1
  for (int h = 0; h < 8; ++h) {
    // ---- stage weight tiles: LINEAR copy of the 48KB frag-order blob
    {
      const char* wb = (const char*)wqf + (size_t)h * 49152 + t * 16;
      const bf16x8 s0 = *reinterpret_cast<const bf16x8*>(wb);
      const bf16x8 s1 = *reinterpret_cast<const bf16x8*>(wb + 8192);
      const bf16x8 s2 = *reinterpret_cast<const bf16x8*>(wb + 16384);
      const bf16x8 s3 = *reinterpret_cast<const bf16x8*>(wb + 24576);
      const bf16x8 s4 = *reinterpret_cast<const bf16x8*>(wb + 32768);
      const bf16x8 s5 = *reinterpret_cast<const bf16x8*>(wb + 40960);
      char* wd = smem + t * 16;
      *reinterpret_cast<bf16x8*>(wd)         = s0;
      *reinterpret_cast<bf16x8*>(wd + 8192)  = s1;
      *reinterpret_cast<bf16x8*>(wd + 16384) = s2;
      *reinterpret_cast<bf16x8*>(wd + 24576) = s3;
      *reinterpret_cast<bf16x8*>(wd + 32768) = s4;
      *reinterpret_cast<bf16x8*>(wd + 40960) = s5;
    }
    __syncthreads();

    // ---- GEMM q & k (share RoPE theta); B reads are base+immediate
    {
      float4v q0a = {0.f,0.f,0.f,0.f}, q1a = q0a, k0a = q0a, k1a = q0a;
#pragma unroll
      for (int s = 0; s < 8; ++s) {
        const bf16x8 bq0 = *reinterpret_cast<const bf16x8*>(smem + bb + s * 2048);
        const bf16x8 bq1 = *reinterpret_cast<const bf16x8*>(smem + bb + s * 2048 + 256);
        const bf16x8 bk0 = *reinterpret_cast<const bf16x8*>(smem + bb + s * 2048 + 16384);
        const bf16x8 bk1 = *reinterpret_cast<const bf16x8*>(smem + bb + s * 2048 + 16384 + 256);
        q0a = mfma16(areg[s], bq0, q0a);
        q1a = mfma16(areg[s], bq1, q1a);
        k0a = mfma16(areg[s], bk0, k0a);
        k1a = mfma16(areg[s], bk1, k1a);
      }
      const float bq0v = bqkv[h * 32 + l15];
      const float bq1v = bqkv[h * 32 + 16 + l15];
      const float bk0v = bqkv[256 + h * 32 + l15];
      const float bk1v = bqkv[256 + h * 32 + 16 + l15];
      const float* Fp = (const float*)(smem + 80384) + (h * 16 + l15) * 3;
      const float F0 = Fp[0], F1 = Fp[1], F2 = Fp[2];
#pragma unroll
      for (int rr = 0; rr < 4; ++rr) {
        const int row  = 16 * w + 4 * g + rr;
        const int prow = ((row & 3) << 5) | (row >> 2);
        const float* xp = (const float*)(smem + 78848) + row * 3;
        const float th = xp[0] * F0 + xp[1] * F1 + xp[2] * F2;
        float rev = th * INV2PI;
        rev -= floorf(rev);
        const float sn = __builtin_amdgcn_sinf(rev);
        const float cs = __builtin_amdgcn_cosf(rev);
        const float q0 = q0a[rr] + bq0v, q1 = q1a[rr] + bq1v;
        const float k0 = k0a[rr] + bk0v, k1 = k1a[rr] + bk1v;
        *reinterpret_cast<unsigned*>(smem + 49152 + prow * 80 + 4 * l15) =
            pack2bf(q0 * cs - q1 * sn, q1 * cs + q0 * sn);
        *reinterpret_cast<unsigned*>(smem + 59392 + prow * 80 + 4 * l15) =
            pack2bf(k0 * cs - k1 * sn, k1 * cs + k0 * sn);
      }
    }
    // ---- GEMM v + epilogue (r4-verbatim layout)
    {
      float4v v0a = {0.f,0.f,0.f,0.f}, v1a = v0a;
#pragma unroll
      for (int s = 0; s < 8; ++s) {
        const bf16x8 bv0 = *reinterpret_cast<const bf16x8*>(smem + bb + s * 2048 + 32768);
        const bf16x8 bv1 = *reinterpret_cast<const bf16x8*>(smem + bb + s * 2048 + 32768 + 256);
        v0a = mfma16(areg[s], bv0, v0a);
        v1a = mfma16(areg[s], bv1, v1a);
      }
      const float bv0v = bqkv[512 + h * 32 + l15];
      const float bv1v = bqkv[512 + h * 32 + 16 + l15];
#pragma unroll
      for (int rr = 0; rr < 4; ++rr) {
        const int row = 16 * w + 4 * g + rr;
        const int kk = row >> 2, dd = row & 3;
        const int cpos = (kk < 16) ? (kk << 1) : (((kk - 16) << 1) | 1);
        *reinterpret_cast<unsigned short*>(
            smem + 69632 + l15 * 272 + (dd * 32 + cpos) * 2) = f2bf(v0a[rr] + bv0v);
        *reinterpret_cast<unsigned short*>(
            smem + 69632 + (l15 + 16) * 272 + (dd * 32 + cpos) * 2) = f2bf(v1a[rr] + bv1v);
      }
    }
    __syncthreads();

    // ---- attention: wave = (group d, half), head h (r4 + ones-MFMA)
    {
      const bf16x8 aq = *reinterpret_cast<const bf16x8*>(
          smem + 49152 + (32 * d + 16 * half + l15) * 80 + 16 * g);
      const bf16x8 bk0 = *reinterpret_cast<const bf16x8*>(
          smem + 59392 + (32 * d + l15) * 80 + 16 * g);
      const bf16x8 bk1 = *reinterpret_cast<const bf16x8*>(
          smem + 59392 + (32 * d + 16 + l15) * 80 + 16 * g);
      float4v s0 = {0.f,0.f,0.f,0.f}, s1 = s0;
      s0 = mfma16(aq, bk0, s0);
      s1 = mfma16(aq, bk1, s1);

      char* plw = smem + w * 1280;     // aliases dead q weight tile
#pragma unroll
      for (int rr = 0; rr < 4; ++rr) {
        // scores are O(0.2) -> exp without max-subtraction is safe
        const float p0 = __expf(s0[rr] * SCALE_ + maskf0[rr]);
        const float p1 = __expf(s1[rr] * SCALE_ + maskf1[rr]);
        *reinterpret_cast<unsigned*>(plw + (4 * g + rr) * 80 + 4 * l15) =
            pack2bf(p0, p1);
      }
      const bf16x8 ap = *reinterpret_cast<const bf16x8*>(plw + l15 * 80 + 16 * g);
      const bf16x8 bv0 = *reinterpret_cast<const bf16x8*>(
          smem + 69632 + l15 * 272 + d * 64 + 16 * g);
      const bf16x8 bv1 = *reinterpret_cast<const bf16x8*>(
          smem + 69632 + (l15 + 16) * 272 + d * 64 + 16 * g);
      float4v o0 = {0.f,0.f,0.f,0.f}, o1 = o0, osum = o0;
      osum = mfma16(ap, ones, osum);
      o0   = mfma16(ap, bv0, o0);
      o1   = mfma16(ap, bv1, o1);

      char* ob = (char*)aout + (size_t)b * 131072 + h * 64;
#pragma unroll
      for (int rr = 0; rr < 4; ++rr) {
        const float rs = __builtin_amdgcn_rcpf(osum[rr]);
        const int n_local = (16 * half + 4 * g + rr) * 4 + d;
        *reinterpret_cast<unsigned*>(ob + n_local * 512 + 4 * l15) =
            pack2bf(o0[rr] * rs, o1[rr] * rs);
      }
    }
    __syncthreads();
  }
}

// ------------------------------- K2: proj ----------------------------------
// r4-verbatim (measured at its HBM floor)
#define K2_LDS_BYTES 81920

__global__ __launch_bounds__(512, 4) void k_proj(
    const unsigned short* ain,                       // d_out bf16 (aliases out!)
    const unsigned short* __restrict__ wproj_t,
    const float* __restrict__ bproj,
    float* out) {
  extern __shared__ char smem2[];
  const int b = blockIdx.x, t = threadIdx.x;
  const int lane = t & 63, w = t >> 6;
  const int g = lane >> 4, l15 = lane & 15;

  {
    const char* abase = (const char*)ain + (size_t)b * 131072;
    bf16x8 stg[8];
#pragma unroll
    for (int i = 0; i < 8; ++i)
      stg[i] = *reinterpret_cast<const bf16x8*>(abase + i * 8192 + t * 16);
#pragma unroll
    for (int i = 0; i < 8; ++i)
      *reinterpret_cast<bf16x8*>(smem2 + swz(i * 8192 + t * 16)) = stg[i];
  }
  __syncthreads();

  bf16x8 areg[8];
#pragma unroll
  for (int s = 0; s < 8; ++s)
    areg[s] = *reinterpret_cast<const bf16x8*>(
        smem2 + swz((16 * w + l15) * 512 + s * 64 + g * 16));

#pragma unroll 1
  for (int p = 0; p < 8; ++p) {
    const char* wb = (const char*)wproj_t + p * 16384;
    const bf16x8 s0 = *reinterpret_cast<const bf16x8*>(wb + t * 16);
    const bf16x8 s1 = *reinterpret_cast<const bf16x8*>(wb + 8192 + t * 16);
    __syncthreads();
    *reinterpret_cast<bf16x8*>(smem2 + 65536 + swz(t * 16)) = s0;
    *reinterpret_cast<bf16x8*>(smem2 + 65536 + swz(8192 + t * 16)) = s1;
    __syncthreads();

    float4v acc0 = {0.f,0.f,0.f,0.f}, acc1 = acc0;
#pragma unroll
    for (int s = 0; s < 8; ++s) {
      const int ko = s * 64 + g * 16;
      bf16x8 b0 = *reinterpret_cast<const bf16x8*>(smem2 + 65536 + swz(l15 * 512 + ko));
      bf16x8 b1 = *reinterpret_cast<const bf16x8*>(smem2 + 65536 + swz((l15 + 16) * 512 + ko));
      acc0 = mfma16(areg[s], b0, acc0);
      acc1 = mfma16(areg[s], b1, acc1);
    }
    const int col0 = 32 * p + l15, col1 = col0 + 16;
    const float bb0 = bproj[col0], bb1 = bproj[col1];
#pragma unroll
    for (int rr = 0; rr < 4; ++rr) {
      const int row = 16 * w + 4 * g + rr;
      out[((size_t)b * 128 + row) * 256 + col0] = acc0[rr] + bb0;
      out[((size_t)b * 128 + row) * 256 + col1] = acc1[rr] + bb1;
    }
  }
}

// ----------------------------- launch --------------------------------------
extern "C" void kernel_launch(void* const* d_in, const int* in_sizes, int n_in,
                              void* d_out, int out_size, void* d_ws, size_t ws_size,
                              hipStream_t stream) {
  const float* data  = (const float*)d_in[0];
  const float* xyz   = (const float*)d_in[1];
  const int*   depth = (const int*)d_in[2];
  const float* wqkv  = (const float*)d_in[3];
  const float* bqkv  = (const float*)d_in[4];
  const float* wproj = (const float*)d_in[5];
  const float* bproj = (const float*)d_in[6];
  const float* freqs = (const float*)d_in[7];

  unsigned short* wqkv_f  = (unsigned short*)d_ws;          // frag-ordered blob
  unsigned short* wproj_t = wqkv_f + 768 * 256;             // [co][cpos]

  (void)hipFuncSetAttribute(reinterpret_cast<const void*>(k_fused),
                            hipFuncAttributeMaxDynamicSharedMemorySize, K1_LDS_BYTES);
  (void)hipFuncSetAttribute(reinterpret_cast<const void*>(k_proj),
                            hipFuncAttributeMaxDynamicSharedMemorySize, K2_LDS_BYTES);

  k_prep<<<dim3(1024), dim3(256), 0, stream>>>(wqkv, wproj, wqkv_f, wproj_t);
  k_fused<<<dim3(3125), dim3(512), K1_LDS_BYTES, stream>>>(
      data, xyz, depth, bqkv, freqs, wqkv_f, (unsigned short*)d_out);
  k_proj<<<dim3(3125), dim3(512), K2_LDS_BYTES, stream>>>(
      (const unsigned short*)d_out, wproj_t, bproj, (float*)d_out);
}